// Round 4
// baseline (994.705 us; speedup 1.0000x reference)
//
#include <hip/hip_runtime.h>
#include <hip/hip_fp16.h>
#include <math.h>

#define N_ 4
#define C_ 31
#define H_ 128
#define W_ 128
#define TOTAL (N_*C_*H_*W_)
#define CPAD 32
#define PI_F 3.14159265358979f
#define RHO_F 1.05f
#define INV_RHO (1.0f/1.05f)
#define NORM2 (1.0f/16384.0f)    // 1/(128*128)

__device__ __forceinline__ float2 cmul(float2 a, float2 b){
  return make_float2(a.x*b.x - a.y*b.y, a.x*b.y + a.y*b.x);
}
__device__ __forceinline__ float2 shflx(float2 v, int m){
  return make_float2(__shfl_xor(v.x, m, 64), __shfl_xor(v.y, m, 64));
}
__device__ __forceinline__ float shrinkf(float x, float t){
  return copysignf(fmaxf(fabsf(x) - t, 0.0f), x);
}

__device__ __forceinline__ void make_tw(float2* tw, int t, float sgn, bool sel){
  float s, c;
  sincosf(sgn * 2.0f * PI_F * (float)t / 128.0f, &s, &c);
  tw[0] = make_float2(c, s);
  #pragma unroll
  for (int i = 1; i < 7; ++i){
    int sp = 64 >> i;
    float ang = (!sel || (t & sp)) ? sgn * 2.0f * PI_F * (float)(t & (sp-1)) / (float)(2*sp) : 0.0f;
    sincosf(ang, &s, &c);
    tw[i] = make_float2(c, s);
  }
}

// Forward DIF FFT-128 over a wave; outputs bit-reversed positions.
__device__ __forceinline__ void fft128_fwd(float2& a, float2& b, const float2* twf, int t){
  float2 u = make_float2(a.x + b.x, a.y + b.y);
  float2 d = make_float2(a.x - b.x, a.y - b.y);
  float2 v = cmul(d, twf[0]);
  #pragma unroll
  for (int i = 1; i < 7; ++i){
    int sp = 64 >> i;
    bool up = (t & sp) != 0;
    float2 pu = shflx(u, sp);
    float2 du = up ? make_float2(pu.x - u.x, pu.y - u.y)
                   : make_float2(u.x + pu.x, u.y + pu.y);
    u = cmul(du, twf[i]);
    float2 pv = shflx(v, sp);
    float2 dv = up ? make_float2(pv.x - v.x, pv.y - v.y)
                   : make_float2(v.x + pv.x, v.y + pv.y);
    v = cmul(dv, twf[i]);
  }
  a = u; b = v;
}

// Inverse DIT FFT-128 (unnormalized): bit-reversed in, natural out.
__device__ __forceinline__ void fft128_inv(float2& a, float2& b, const float2* twi, int t){
  float2 u = a, v = b;
  #pragma unroll
  for (int i = 6; i >= 1; --i){
    int sp = 64 >> i;
    bool up = (t & sp) != 0;
    float2 pu = shflx(u, sp);
    float2 e  = up ? pu : u;
    float2 o  = up ? u  : pu;
    float2 wo = cmul(o, twi[i]);
    u = up ? make_float2(e.x - wo.x, e.y - wo.y)
           : make_float2(e.x + wo.x, e.y + wo.y);
    float2 pv = shflx(v, sp);
    float2 ev = up ? pv : v;
    float2 ov = up ? v  : pv;
    float2 wv = cmul(ov, twi[i]);
    v = up ? make_float2(ev.x - wv.x, ev.y - wv.y)
           : make_float2(ev.x + wv.x, ev.y + wv.y);
  }
  float2 tv = cmul(v, twi[0]);
  a = make_float2(u.x + tv.x, u.y + tv.y);
  b = make_float2(u.x - tv.x, u.y - tv.y);
}

// K0: one-time pack of (Y, inW) into half2.
__global__ __launch_bounds__(256) void kern_pack(const float* __restrict__ Y,
    const float* __restrict__ W, __half2* __restrict__ YW)
{
  int i = blockIdx.x * 256 + threadIdx.x;
  YW[i] = __floats2half2_rn(Y[i], W[i]);
}

// K1: fused V-update (ping-pong, fp16) + numer + W-FFT -> A (fp16).
// Block: (pair, h, c-chunk of 8). 512 threads = 8 waves.
__global__ __launch_bounds__(512,4) void kern_fwdW(
    const float* __restrict__ Z, const float* __restrict__ Q,
    const __half* __restrict__ Vhi, const __half* __restrict__ Vvi, const __half* __restrict__ Vsi,
    __half* __restrict__ Vho, __half* __restrict__ Vvo, __half* __restrict__ Vso,
    __half2* __restrict__ A, float thr, int first)
{
  __shared__ float sVh [8][2][128];   // Vh(c0+i, h)
  __shared__ float sVvH[8][2][128];   // Vv(c0+i, h)
  __shared__ float sVvM[8][2][128];   // Vv(c0+i, h-1)
  __shared__ float sVs [9][2][128];   // Vs(c0-1+i, h)
  __shared__ float tre[8][130], tim[8][130];
  int tid = threadIdx.x, lane = tid & 63, wv = tid >> 6;
  int b = blockIdx.x;
  int chunk = b & 3, h = (b >> 2) & (H_-1), pair = b >> 9;
  int c0 = chunk * 8;
  int hm1 = (h + H_-1) & (H_-1);

  // ---- phase 1: 34 wave-tasks (17 rows x 2 packed volumes) ----
  for (int t = wv; t < 34; t += 8){
    int vol = t & 1, rid = t >> 1;
    bool typeA = (rid < 9);
    int c  = typeA ? (c0 - 1 + rid) : (c0 + rid - 9);
    if (c < 0) c += C_;
    if (c >= C_) continue;
    int hh = typeA ? h : hm1;
    int vn = 2*pair + vol;
    long zb = (((long)vn*C_ + c)*H_ + hh)*W_;
    int hp1 = (hh + 1) & (H_-1);
    long zv = zb + ((long)hp1 - hh)*W_;
    const float aa = 1.0f + INV_RHO;
    if (typeA){
      int cp1 = (c+1 == C_) ? 0 : c+1;
      long zc = (((long)vn*C_ + cp1)*H_ + hh)*W_;
      #pragma unroll
      for (int e = 0; e < 2; ++e){
        int w = lane + 64*e;
        int wp = (w+1) & (W_-1);
        float z0 = Z[zb+w];
        float Dh = z0 - Z[zb+wp];
        float Dv = z0 - Z[zv+w];
        float Ds = z0 - Z[zc+w];
        float vh, vv, vs;
        if (first){
          vh = shrinkf(Dh,thr); vv = shrinkf(Dv,thr); vs = shrinkf(Ds,thr);
        } else {
          float oh = __half2float(Vhi[zb+w]);
          float ov = __half2float(Vvi[zb+w]);
          float os = __half2float(Vsi[zb+w]);
          vh = shrinkf(aa*Dh - oh*INV_RHO, thr) + (oh - Dh)*INV_RHO;
          vv = shrinkf(aa*Dv - ov*INV_RHO, thr) + (ov - Dv)*INV_RHO;
          vs = shrinkf(aa*Ds - os*INV_RHO, thr) + (os - Ds)*INV_RHO;
        }
        sVs[rid][vol][w] = vs;
        if (rid >= 1){
          sVh [rid-1][vol][w] = vh;
          sVvH[rid-1][vol][w] = vv;
          Vho[zb+w] = __float2half(vh);
          Vvo[zb+w] = __float2half(vv);
          Vso[zb+w] = __float2half(vs);
        }
      }
    } else {
      #pragma unroll
      for (int e = 0; e < 2; ++e){
        int w = lane + 64*e;
        float z0 = Z[zb+w];
        float Dv = z0 - Z[zv+w];
        float vv;
        if (first){
          vv = shrinkf(Dv, thr);
        } else {
          float ov = __half2float(Vvi[zb+w]);
          vv = shrinkf(aa*Dv - ov*INV_RHO, thr) + (ov - Dv)*INV_RHO;
        }
        sVvM[rid-9][vol][w] = vv;
      }
    }
  }
  __syncthreads();

  // ---- phase 2: numer + W-FFT, wave r owns c = c0 + r ----
  int r = wv, c = c0 + r;
  if (c < C_){
    float2 twf[7];
    make_tw(twf, lane, -1.0f, true);
    long b0 = (((long)(2*pair)*C_ + c)*H_ + h)*W_;
    long b1 = b0 + (long)C_*H_*W_;
    float2 ab[2];
    #pragma unroll
    for (int e = 0; e < 2; ++e){
      int w = lane + 64*e;
      int wm1 = (w + W_-1) & (W_-1);
      float re = Q[b0+w] + (sVh[r][0][w] - sVh[r][0][wm1])
               + (sVvH[r][0][w] - sVvM[r][0][w]) + (sVs[r+1][0][w] - sVs[r][0][w]);
      float im = Q[b1+w] + (sVh[r][1][w] - sVh[r][1][wm1])
               + (sVvH[r][1][w] - sVvM[r][1][w]) + (sVs[r+1][1][w] - sVs[r][1][w]);
      ab[e] = make_float2(re, im);
    }
    fft128_fwd(ab[0], ab[1], twf, lane);
    tre[r][lane]    = ab[0].x; tim[r][lane]    = ab[0].y;
    tre[r][lane+64] = ab[1].x; tim[r][lane+64] = ab[1].y;
  }
  __syncthreads();

  // ---- transpose-store to A[pair][w][h][CPAD] in fp16 ----
  int ws = tid >> 2, q = tid & 3, cA = 2*q;
  long abase = (((long)pair*W_ + ws)*H_ + h)*CPAD + c0 + cA;
  if (c0 + cA + 1 < C_){
    A[abase]   = __floats2half2_rn(tre[cA][ws],   tim[cA][ws]);
    A[abase+1] = __floats2half2_rn(tre[cA+1][ws], tim[cA+1][ws]);
  } else if (c0 + cA < C_){
    A[abase]   = __floats2half2_rn(tre[cA][ws],   tim[cA][ws]);
  }
}

// K2: H-FFT fwd + 25-tap circulant c-solve + H-FFT inv, per (pair, w) slab.
__global__ __launch_bounds__(1024) void kern_CH(__half2* __restrict__ A)
{
  __shared__ float2 slab[H_][C_];
  int tid = threadIdx.x, lane = tid & 63, wv = tid >> 6;
  int bid = blockIdx.x;                 // pair*128 + w
  int w = bid & (W_-1);
  __half2* g = A + (long)bid * H_ * CPAD;
  float2* sl = &slab[0][0];

  for (int i = tid; i < H_*C_; i += 1024){
    int hh = i / C_;
    int cc = i - hh*C_;
    float2 v = __half22float2(g[(hh << 5) + cc]);
    sl[i] = v;
  }
  float2 twf[7], twi[7];
  make_tw(twf, lane, -1.0f, true);
  make_tw(twi, lane, +1.0f, false);
  __syncthreads();

  #pragma unroll
  for (int rr = 0; rr < 2; ++rr){
    int c = wv + 16*rr;
    if (c < C_){
      float2 a = slab[lane][c], b = slab[lane+64][c];
      fft128_fwd(a, b, twf, lane);
      slab[lane][c] = a; slab[lane+64][c] = b;
    }
  }
  __syncthreads();

  {
    int col = tid & (H_-1), cb = tid >> 7, c0 = cb * 4;
    int fh = __brev(col) >> 25;
    int fw = __brev(w)   >> 25;
    float dh = 2.0f - 2.0f * cosf(2.0f * PI_F * (float)fh / 128.0f);
    float dw = 2.0f - 2.0f * cosf(2.0f * PI_F * (float)fw / 128.0f);
    float beta = 1.0f + dh + dw;
    float a2 = beta + 2.0f;
    float s  = sqrtf(a2*a2 - 4.0f);
    float rg = (a2 - s) * 0.5f;
    float gt[13];
    gt[0] = NORM2 / s;
    #pragma unroll
    for (int t = 1; t < 13; ++t) gt[t] = gt[t-1] * rg;

    float2 win[28];
    #pragma unroll
    for (int i = 0; i < 28; ++i){
      int ci = c0 - 12 + i;
      if (ci < 0) ci += C_;
      if (ci >= C_) ci -= C_;
      win[i] = slab[col][ci];
    }
    float2 out[4];
    #pragma unroll
    for (int j = 0; j < 4; ++j){
      float ox = 0.0f, oy = 0.0f;
      #pragma unroll
      for (int t = -12; t <= 12; ++t){
        float gv = gt[t < 0 ? -t : t];
        float2 xv = win[j + 12 - t];
        ox += gv * xv.x;
        oy += gv * xv.y;
      }
      out[j] = make_float2(ox, oy);
    }
    __syncthreads();
    #pragma unroll
    for (int j = 0; j < 4; ++j){
      int c = c0 + j;
      if (c < C_) slab[col][c] = out[j];
    }
  }
  __syncthreads();

  #pragma unroll
  for (int rr = 0; rr < 2; ++rr){
    int c = wv + 16*rr;
    if (c < C_){
      float2 a = slab[lane][c], b = slab[lane+64][c];
      fft128_inv(a, b, twi, lane);
      slab[lane][c] = a; slab[lane+64][c] = b;
    }
  }
  __syncthreads();
  for (int i = tid; i < H_*C_; i += 1024){
    int hh = i / C_;
    int cc = i - hh*C_;
    float2 v = sl[i];
    g[(hh << 5) + cc] = __floats2half2_rn(v.x, v.y);
  }
}

// K3: A load -> LDS transpose -> inverse W-FFT -> Z + fused X/G1/Q update.
__global__ __launch_bounds__(512,4) void kern_invW(const __half2* __restrict__ A,
    float* __restrict__ Z, const __half2* __restrict__ YW,
    float* __restrict__ G1, float* __restrict__ Qo,
    float mu, int first, int last)
{
  __shared__ float tre[8][130], tim[8][130];
  int tid = threadIdx.x, lane = tid & 63, r = tid >> 6;
  int b = blockIdx.x;
  int chunk = b & 3, h = (b >> 2) & (H_-1), pair = b >> 9;
  int c0 = chunk * 8;
  {
    int ws = tid >> 2, q = tid & 3, cA = 2*q;
    long abase = (((long)pair*W_ + ws)*H_ + h)*CPAD + c0 + cA;
    if (c0 + cA + 1 < C_){
      float2 v0 = __half22float2(A[abase]);
      float2 v1 = __half22float2(A[abase+1]);
      tre[cA][ws] = v0.x; tim[cA][ws] = v0.y;
      tre[cA+1][ws] = v1.x; tim[cA+1][ws] = v1.y;
    } else if (c0 + cA < C_){
      float2 v0 = __half22float2(A[abase]);
      tre[cA][ws] = v0.x; tim[cA][ws] = v0.y;
    }
  }
  __syncthreads();
  int c = c0 + r;
  if (c >= C_) return;
  float2 twi[7];
  make_tw(twi, lane, +1.0f, false);
  float2 a  = make_float2(tre[r][lane],    tim[r][lane]);
  float2 bb = make_float2(tre[r][lane+64], tim[r][lane+64]);
  fft128_inv(a, bb, twi, lane);

  long base0 = (((long)(2*pair)*C_ + c)*H_ + h)*W_;
  long base1 = base0 + (long)C_*H_*W_;
  float zs[4] = {a.x, a.y, bb.x, bb.y};
  long ps[4]  = {base0 + lane, base1 + lane, base0 + lane + 64, base1 + lane + 64};
  #pragma unroll
  for (int qq = 0; qq < 4; ++qq){
    long p = ps[qq];
    float z = zs[qq];
    Z[p] = z;
    if (!last){
      float2 yw = __half22float2(YW[p]);
      float y = yw.x, iw = yw.y;
      float g1 = first ? 0.0f : G1[p];
      float x = (iw*y + mu*z - g1) / (iw + mu);
      float g1n = g1 + mu*(x - z);
      G1[p] = g1n;
      Qo[p] = x + g1n / (mu * RHO_F);
    }
  }
}

extern "C" void kernel_launch(void* const* d_in, const int* in_sizes, int n_in,
                              void* d_out, int out_size, void* d_ws, size_t ws_size,
                              hipStream_t stream)
{
  const float* Y   = (const float*)d_in[0];
  const float* inW = (const float*)d_in[1];
  float* Z = (float*)d_out;

  float*   Q   = (float*)d_ws;
  float*   G1  = Q  + TOTAL;
  __half2* YW  = (__half2*)(G1 + TOTAL);
  __half*  V0h = (__half*)(YW + TOTAL);
  __half*  V0v = V0h + TOTAL;
  __half*  V0s = V0v + TOTAL;
  __half*  V1h = V0s + TOTAL;
  __half*  V1v = V1h + TOTAL;
  __half*  V1s = V1v + TOTAL;
  __half2* A   = (__half2*)(V1s + TOTAL);

  kern_pack<<<dim3(TOTAL/256), dim3(256), 0, stream>>>(Y, inW, YW);

  float mu = 0.1f;
  for (int it = 0; it < 20; ++it){
    int first = (it == 0) ? 1 : 0;
    int last  = (it == 19) ? 1 : 0;
    float thr = 0.1f / mu;
    const float* Zs = first ? Y : (const float*)Z;
    const float* Qs = first ? Y : (const float*)Q;
    int cur = it & 1;
    const __half* Vhi = cur ? V1h : V0h;
    const __half* Vvi = cur ? V1v : V0v;
    const __half* Vsi = cur ? V1s : V0s;
    __half* Vho = cur ? V0h : V1h;
    __half* Vvo = cur ? V0v : V1v;
    __half* Vso = cur ? V0s : V1s;

    kern_fwdW<<<dim3(2*H_*4), dim3(512),  0, stream>>>(Zs, Qs, Vhi, Vvi, Vsi,
                                                       Vho, Vvo, Vso, A, thr, first);
    kern_CH  <<<dim3(2*W_),   dim3(1024), 0, stream>>>(A);
    kern_invW<<<dim3(2*H_*4), dim3(512),  0, stream>>>(A, Z, YW, G1, Q, mu, first, last);

    mu *= 1.05f;
  }
}

// Round 5
// 804.655 us; speedup vs baseline: 1.2362x; 1.2362x over previous
//
#include <hip/hip_runtime.h>
#include <hip/hip_fp16.h>
#include <math.h>

#define N_ 4
#define C_ 31
#define H_ 128
#define W_ 128
#define TOTAL (N_*C_*H_*W_)
#define CV_ (C_*H_*W_)
#define PI_F 3.14159265358979f
#define RHO_F 1.05f
#define INV_RHO (1.0f/1.05f)
#define NORM2 (1.0f/16384.0f)    // 1/(128*128)

__device__ __forceinline__ float2 cmul(float2 a, float2 b){
  return make_float2(a.x*b.x - a.y*b.y, a.x*b.y + a.y*b.x);
}
__device__ __forceinline__ float2 shflx(float2 v, int m){
  return make_float2(__shfl_xor(v.x, m, 64), __shfl_xor(v.y, m, 64));
}
__device__ __forceinline__ float shrinkf(float x, float t){
  return copysignf(fmaxf(fabsf(x) - t, 0.0f), x);
}

__device__ __forceinline__ void make_tw(float2* tw, int t, float sgn, bool sel){
  float s, c;
  sincosf(sgn * 2.0f * PI_F * (float)t / 128.0f, &s, &c);
  tw[0] = make_float2(c, s);
  #pragma unroll
  for (int i = 1; i < 7; ++i){
    int sp = 64 >> i;
    float ang = (!sel || (t & sp)) ? sgn * 2.0f * PI_F * (float)(t & (sp-1)) / (float)(2*sp) : 0.0f;
    sincosf(ang, &s, &c);
    tw[i] = make_float2(c, s);
  }
}

// Forward DIF FFT-128 over a wave; outputs bit-reversed positions.
__device__ __forceinline__ void fft128_fwd(float2& a, float2& b, const float2* twf, int t){
  float2 u = make_float2(a.x + b.x, a.y + b.y);
  float2 d = make_float2(a.x - b.x, a.y - b.y);
  float2 v = cmul(d, twf[0]);
  #pragma unroll
  for (int i = 1; i < 7; ++i){
    int sp = 64 >> i;
    bool up = (t & sp) != 0;
    float2 pu = shflx(u, sp);
    float2 du = up ? make_float2(pu.x - u.x, pu.y - u.y)
                   : make_float2(u.x + pu.x, u.y + pu.y);
    u = cmul(du, twf[i]);
    float2 pv = shflx(v, sp);
    float2 dv = up ? make_float2(pv.x - v.x, pv.y - v.y)
                   : make_float2(v.x + pv.x, v.y + pv.y);
    v = cmul(dv, twf[i]);
  }
  a = u; b = v;
}

// Inverse DIT FFT-128 (unnormalized): bit-reversed in, natural out.
__device__ __forceinline__ void fft128_inv(float2& a, float2& b, const float2* twi, int t){
  float2 u = a, v = b;
  #pragma unroll
  for (int i = 6; i >= 1; --i){
    int sp = 64 >> i;
    bool up = (t & sp) != 0;
    float2 pu = shflx(u, sp);
    float2 e  = up ? pu : u;
    float2 o  = up ? u  : pu;
    float2 wo = cmul(o, twi[i]);
    u = up ? make_float2(e.x - wo.x, e.y - wo.y)
           : make_float2(e.x + wo.x, e.y + wo.y);
    float2 pv = shflx(v, sp);
    float2 ev = up ? pv : v;
    float2 ov = up ? v  : pv;
    float2 wv = cmul(ov, twi[i]);
    v = up ? make_float2(ev.x - wv.x, ev.y - wv.y)
           : make_float2(ev.x + wv.x, ev.y + wv.y);
  }
  float2 tv = cmul(v, twi[0]);
  a = make_float2(u.x + tv.x, u.y + tv.y);
  b = make_float2(u.x - tv.x, u.y - tv.y);
}

// K0: one-time pack of (Y, inW) into half2.
__global__ __launch_bounds__(256) void kern_pack(const float* __restrict__ Y,
    const float* __restrict__ W, __half2* __restrict__ YW)
{
  int i = blockIdx.x * 256 + threadIdx.x;
  YW[i] = __floats2half2_rn(Y[i], W[i]);
}

// K1: V-field update, in place, fp16, 4 w per thread.
__global__ __launch_bounds__(256) void kern_V(const float* __restrict__ Z,
    __half2* __restrict__ Vh, __half2* __restrict__ Vv, __half2* __restrict__ Vs,
    float thr, int first)
{
  int t = blockIdx.x * 256 + threadIdx.x;       // one per 4 elements
  int base = t * 4;
  int w0 = base & (W_-1);
  int h  = (base >> 7) & (H_-1);
  int nc = base >> 14;
  int c  = nc % C_;
  float4 z = *(const float4*)(Z + base);
  float z4 = (w0 + 4 == W_) ? Z[base - (W_-4)] : Z[base + 4];
  int hp1 = (h + 1) & (H_-1);
  float4 zv = *(const float4*)(Z + base + (hp1 - h)*W_);
  int cofs = (c == C_-1) ? -(C_-1)*(H_*W_) : H_*W_;
  float4 zc = *(const float4*)(Z + base + cofs);

  float Dh[4] = {z.x - z.y, z.y - z.z, z.z - z.w, z.w - z4};
  float Dv[4] = {z.x - zv.x, z.y - zv.y, z.z - zv.z, z.w - zv.w};
  float Ds[4] = {z.x - zc.x, z.y - zc.y, z.z - zc.z, z.w - zc.w};

  int hb = t * 2;                                // half2 index
  float vh[4], vv[4], vs[4];
  if (first){
    #pragma unroll
    for (int j = 0; j < 4; ++j){
      vh[j] = shrinkf(Dh[j], thr);
      vv[j] = shrinkf(Dv[j], thr);
      vs[j] = shrinkf(Ds[j], thr);
    }
  } else {
    const float aa = 1.0f + INV_RHO;
    float2 oh0 = __half22float2(Vh[hb]), oh1 = __half22float2(Vh[hb+1]);
    float2 ov0 = __half22float2(Vv[hb]), ov1 = __half22float2(Vv[hb+1]);
    float2 os0 = __half22float2(Vs[hb]), os1 = __half22float2(Vs[hb+1]);
    float oh[4] = {oh0.x, oh0.y, oh1.x, oh1.y};
    float ov[4] = {ov0.x, ov0.y, ov1.x, ov1.y};
    float os[4] = {os0.x, os0.y, os1.x, os1.y};
    #pragma unroll
    for (int j = 0; j < 4; ++j){
      vh[j] = shrinkf(aa*Dh[j] - oh[j]*INV_RHO, thr) + (oh[j] - Dh[j])*INV_RHO;
      vv[j] = shrinkf(aa*Dv[j] - ov[j]*INV_RHO, thr) + (ov[j] - Dv[j])*INV_RHO;
      vs[j] = shrinkf(aa*Ds[j] - os[j]*INV_RHO, thr) + (os[j] - Ds[j])*INV_RHO;
    }
  }
  Vh[hb]   = __floats2half2_rn(vh[0], vh[1]);
  Vh[hb+1] = __floats2half2_rn(vh[2], vh[3]);
  Vv[hb]   = __floats2half2_rn(vv[0], vv[1]);
  Vv[hb+1] = __floats2half2_rn(vv[2], vv[3]);
  Vs[hb]   = __floats2half2_rn(vs[0], vs[1]);
  Vs[hb+1] = __floats2half2_rn(vs[2], vs[3]);
}

// K2: numer + W-FFT -> A[pair][w][c][h] (fp16 complex), coalesced via LDS transpose.
// Block = (pair, c, h-tile of 8); 256 threads = 4 waves, 2 rows per wave.
__global__ __launch_bounds__(256) void kern_fwdW(
    const float* __restrict__ Yfirst, const __half* __restrict__ Qh,
    const __half* __restrict__ Vh, const __half* __restrict__ Vv, const __half* __restrict__ Vs,
    __half2* __restrict__ A, int first)
{
  __shared__ __half2 buf[8][128];      // [h_local][w-position]
  int tid = threadIdx.x, lane = tid & 63, wv = tid >> 6;
  int b = blockIdx.x;                  // ((pair*31 + c)*16 + ht)
  int ht = b & 15, c = (b >> 4) % C_, pair = b / (16*C_);
  int h0 = ht * 8;

  float2 twf[7];
  make_tw(twf, lane, -1.0f, true);
  int cm1 = (c == 0) ? (C_-1) : (c-1);

  #pragma unroll
  for (int r = 0; r < 2; ++r){
    int hl = wv + 4*r;
    int h = h0 + hl;
    int hm1 = (h + H_-1) & (H_-1);
    long b0 = ((long)c*H_ + h)*W_ + (long)(2*pair)*CV_;
    long b1 = b0 + CV_;
    long ofsVv = ((long)hm1 - h)*W_;
    long ofsVs = ((long)cm1 - c)*H_*W_;
    float2 ab[2];
    #pragma unroll
    for (int e = 0; e < 2; ++e){
      int w = lane + 64*e;
      long p0 = b0 + w, p1 = b1 + w;
      float q0 = first ? Yfirst[p0] : __half2float(Qh[p0]);
      float q1 = first ? Yfirst[p1] : __half2float(Qh[p1]);
      float vh0 = __half2float(Vh[p0]), vh1 = __half2float(Vh[p1]);
      float vv0 = __half2float(Vv[p0]), vv1 = __half2float(Vv[p1]);
      float vvm0 = __half2float(Vv[p0+ofsVv]), vvm1 = __half2float(Vv[p1+ofsVv]);
      float vs0 = __half2float(Vs[p0]), vs1 = __half2float(Vs[p1]);
      float vsm0 = __half2float(Vs[p0+ofsVs]), vsm1 = __half2float(Vs[p1+ofsVs]);
      ab[e] = make_float2(q0 + vh0 + (vv0 - vvm0) + (vs0 - vsm0),
                          q1 + vh1 + (vv1 - vvm1) + (vs1 - vsm1));
    }
    // subtract Vh[w-1] via cross-lane shuffle (w=0 wraps to w=127)
    {
      float vha0 = __half2float(Vh[b0 + lane]);
      float vhb0 = __half2float(Vh[b0 + lane + 64]);
      float vha1 = __half2float(Vh[b1 + lane]);
      float vhb1 = __half2float(Vh[b1 + lane + 64]);
      // prev for a-half (w=lane): lane-1, lane0 <- b-half lane63 (w=127)
      float pa0 = __shfl(vha0, lane-1, 64), pb0 = __shfl(vhb0, lane-1, 64);
      float pa1 = __shfl(vha1, lane-1, 64), pb1 = __shfl(vhb1, lane-1, 64);
      float wrap0 = __shfl(vhb0, 63, 64), wrap1 = __shfl(vhb1, 63, 64);
      float mid0  = __shfl(vha0, 63, 64), mid1  = __shfl(vha1, 63, 64);
      float am0 = (lane == 0) ? wrap0 : pa0;
      float am1 = (lane == 0) ? wrap1 : pa1;
      float bm0 = (lane == 0) ? mid0 : pb0;
      float bm1 = (lane == 0) ? mid1 : pb1;
      ab[0].x -= am0; ab[0].y -= am1;
      ab[1].x -= bm0; ab[1].y -= bm1;
    }
    fft128_fwd(ab[0], ab[1], twf, lane);
    buf[hl][lane]    = __floats2half2_rn(ab[0].x, ab[0].y);
    buf[hl][lane+64] = __floats2half2_rn(ab[1].x, ab[1].y);
  }
  __syncthreads();
  // store: int4 = 4 consecutive h for one (w-position p, c)
  int4* A4 = (int4*)A;
  for (int i = tid; i < 256; i += 256){
    int p = i >> 1, hq = i & 1;
    union { int4 v; __half2 e[4]; } u;
    #pragma unroll
    for (int j = 0; j < 4; ++j) u.e[j] = buf[4*hq + j][p];
    long idx4 = (((long)pair*W_ + p)*C_ + c)*(H_/4) + 2*ht + hq;
    A4[idx4] = u.v;
  }
}

// K3: slab [c][h] load (contiguous) -> H-FFT fwd -> 25-tap circulant c-solve -> H-FFT inv -> store.
__global__ __launch_bounds__(1024) void kern_CH(__half2* __restrict__ A)
{
  __shared__ float2 slab[C_][H_];
  int tid = threadIdx.x, lane = tid & 63, wv = tid >> 6;
  int bid = blockIdx.x;                 // pair*128 + w
  int w = bid & (W_-1);
  const int4* g4 = (const int4*)(A + (long)bid * C_ * H_);

  if (tid < 992){
    union { int4 v; __half2 e[4]; } u;
    u.v = g4[tid];
    int c = tid >> 5, hb = (tid & 31) << 2;
    #pragma unroll
    for (int j = 0; j < 4; ++j){
      float2 f = __half22float2(u.e[j]);
      slab[c][hb+j] = f;
    }
  }
  float2 twf[7], twi[7];
  make_tw(twf, lane, -1.0f, true);
  make_tw(twi, lane, +1.0f, false);
  __syncthreads();

  #pragma unroll
  for (int rr = 0; rr < 2; ++rr){
    int c = wv + 16*rr;
    if (c < C_){
      float2 a = slab[c][lane], b = slab[c][lane+64];
      fft128_fwd(a, b, twf, lane);
      slab[c][lane] = a; slab[c][lane+64] = b;
    }
  }
  __syncthreads();

  {
    int col = tid & (H_-1), cb = tid >> 7, c0 = cb * 4;
    int fh = __brev(col) >> 25;
    int fw = __brev(w)   >> 25;
    float dh = 2.0f - 2.0f * cosf(2.0f * PI_F * (float)fh / 128.0f);
    float dw = 2.0f - 2.0f * cosf(2.0f * PI_F * (float)fw / 128.0f);
    float beta = 1.0f + dh + dw;
    float a2 = beta + 2.0f;
    float s  = sqrtf(a2*a2 - 4.0f);
    float rg = (a2 - s) * 0.5f;
    float gt[13];
    gt[0] = NORM2 / s;
    #pragma unroll
    for (int t = 1; t < 13; ++t) gt[t] = gt[t-1] * rg;

    float2 win[28];
    #pragma unroll
    for (int i = 0; i < 28; ++i){
      int ci = c0 - 12 + i;
      if (ci < 0) ci += C_;
      if (ci >= C_) ci -= C_;
      win[i] = slab[ci][col];
    }
    float2 out[4];
    #pragma unroll
    for (int j = 0; j < 4; ++j){
      float ox = 0.0f, oy = 0.0f;
      #pragma unroll
      for (int t = -12; t <= 12; ++t){
        float gv = gt[t < 0 ? -t : t];
        float2 xv = win[j + 12 - t];
        ox += gv * xv.x;
        oy += gv * xv.y;
      }
      out[j] = make_float2(ox, oy);
    }
    __syncthreads();
    #pragma unroll
    for (int j = 0; j < 4; ++j){
      int c = c0 + j;
      if (c < C_) slab[c][col] = out[j];
    }
  }
  __syncthreads();

  #pragma unroll
  for (int rr = 0; rr < 2; ++rr){
    int c = wv + 16*rr;
    if (c < C_){
      float2 a = slab[c][lane], b = slab[c][lane+64];
      fft128_inv(a, b, twi, lane);
      slab[c][lane] = a; slab[c][lane+64] = b;
    }
  }
  __syncthreads();
  int4* go4 = (int4*)(A + (long)bid * C_ * H_);
  if (tid < 992){
    int c = tid >> 5, hb = (tid & 31) << 2;
    union { int4 v; __half2 e[4]; } u;
    #pragma unroll
    for (int j = 0; j < 4; ++j){
      float2 f = slab[c][hb+j];
      u.e[j] = __floats2half2_rn(f.x, f.y);
    }
    go4[tid] = u.v;
  }
}

// K4: coalesced A load -> LDS -> inverse W-FFT per wave-row -> Z + fused X/G1/Q (fp16 G1,Q).
__global__ __launch_bounds__(256) void kern_invW(const __half2* __restrict__ A,
    float* __restrict__ Z, const __half2* __restrict__ YW,
    __half* __restrict__ G1, __half* __restrict__ Qh,
    float mu, int first, int last)
{
  __shared__ __half2 buf[8][128];
  int tid = threadIdx.x, lane = tid & 63, wv = tid >> 6;
  int b = blockIdx.x;
  int ht = b & 15, c = (b >> 4) % C_, pair = b / (16*C_);
  int h0 = ht * 8;

  const int4* A4 = (const int4*)A;
  for (int i = tid; i < 256; i += 256){
    int p = i >> 1, hq = i & 1;
    long idx4 = (((long)pair*W_ + p)*C_ + c)*(H_/4) + 2*ht + hq;
    union { int4 v; __half2 e[4]; } u;
    u.v = A4[idx4];
    #pragma unroll
    for (int j = 0; j < 4; ++j) buf[4*hq + j][p] = u.e[j];
  }
  __syncthreads();

  float2 twi[7];
  make_tw(twi, lane, +1.0f, false);

  #pragma unroll
  for (int r = 0; r < 2; ++r){
    int hl = wv + 4*r;
    int h = h0 + hl;
    float2 a = __half22float2(buf[hl][lane]);
    float2 bb = __half22float2(buf[hl][lane+64]);
    fft128_inv(a, bb, twi, lane);

    long b0 = ((long)c*H_ + h)*W_ + (long)(2*pair)*CV_;
    long b1 = b0 + CV_;
    float zs[4] = {a.x, a.y, bb.x, bb.y};
    long ps[4]  = {b0 + lane, b1 + lane, b0 + lane + 64, b1 + lane + 64};
    #pragma unroll
    for (int qq = 0; qq < 4; ++qq){
      long p = ps[qq];
      float z = zs[qq];
      Z[p] = z;
      if (!last){
        float2 yw = __half22float2(YW[p]);
        float y = yw.x, iw = yw.y;
        float g1 = first ? 0.0f : __half2float(G1[p]);
        float x = (iw*y + mu*z - g1) / (iw + mu);
        float g1n = g1 + mu*(x - z);
        G1[p] = __float2half(g1n);
        Qh[p] = __float2half(x + g1n / (mu * RHO_F));
      }
    }
  }
}

extern "C" void kernel_launch(void* const* d_in, const int* in_sizes, int n_in,
                              void* d_out, int out_size, void* d_ws, size_t ws_size,
                              hipStream_t stream)
{
  const float* Y   = (const float*)d_in[0];
  const float* inW = (const float*)d_in[1];
  float* Z = (float*)d_out;

  __half2* YW = (__half2*)d_ws;                 // TOTAL half2
  __half*  Qh = (__half*)(YW + TOTAL);
  __half*  G1 = Qh + TOTAL;
  __half*  Vh = G1 + TOTAL;
  __half*  Vv = Vh + TOTAL;
  __half*  Vs = Vv + TOTAL;
  __half2* A  = (__half2*)(Vs + TOTAL);         // [2][128][31][128] half2 = 4.06 MB

  kern_pack<<<dim3(TOTAL/256), dim3(256), 0, stream>>>(Y, inW, YW);

  float mu = 0.1f;
  for (int it = 0; it < 20; ++it){
    int first = (it == 0) ? 1 : 0;
    int last  = (it == 19) ? 1 : 0;
    float thr = 0.1f / mu;
    const float* Zs = first ? Y : (const float*)Z;

    kern_V   <<<dim3(TOTAL/1024), dim3(256),  0, stream>>>(Zs,
                 (__half2*)Vh, (__half2*)Vv, (__half2*)Vs, thr, first);
    kern_fwdW<<<dim3(2*C_*16),    dim3(256),  0, stream>>>(Y, Qh, Vh, Vv, Vs, A, first);
    kern_CH  <<<dim3(2*W_),       dim3(1024), 0, stream>>>(A);
    kern_invW<<<dim3(2*C_*16),    dim3(256),  0, stream>>>(A, Z, YW, G1, Qh, mu, first, last);

    mu *= 1.05f;
  }
}